// Round 7
// baseline (221.628 us; speedup 1.0000x reference)
//
#include <hip/hip_runtime.h>
#include <hip/hip_bf16.h>
#include <stdint.h>

// RecursiveDecoder. M=128, H=F=256, T=4, ITERS=2, NSEM=57.
// R6->R7: 7 -> 5 kernels via per-row fusion (block owns full cf_next row):
//   k1   cf0 = relu(pf @ W_parent + b)            [37 MB, HBM-bound]
//   ks1  A,B = cf0@W_el | P0,Q0 = cf0@Wne0 | exists logits | W3T bf16 pack
//   k3   EL = relu(A[i]+B[j]+bel) -> ELbf (bf16 swizzled) + edge logits (fp32)
//   kf<0> row-block GEMM(ELbf@W3, MFMA) + masked scatter-max -> cf1
//        epilogue: P1,Q1 = cf1_row @ Wne1  (kp1 fused; separate Pb2/Qb2 buffers)
//   kf<1> same GEMM it1 -> cf2; epilogue: h=relu([cf0|cf1|cf2]@Wc+bc),
//        out_co=relu(h@W2+b2), sem=h@Wsem+bsem  (k6_final fused)
// Mask-critical (exists/edge logits) fp32; only EL->R path bf16 MFMA.
// ws: cf0 0 | cf1 128K | cf2 256K | A 384K | B 512K | P 640K | Q 768K |
//     Pb2 896K | Qb2 1M | ex0 1.125M | W3T 1.25M (256K) | ELbf 2M (8M)

typedef unsigned short ushort_t;
using f32x4 = __attribute__((ext_vector_type(4))) float;
using s16x8 = __attribute__((ext_vector_type(8))) short;

__device__ __forceinline__ ushort_t f2bf(float x) {
  __hip_bfloat16 h = __float2bfloat16(x);
  return *reinterpret_cast<ushort_t*>(&h);
}

// ---------- k1: cf0 = relu(pf @ W_parent + b). 1024 blocks x (8 f4-cols, 32 k-slices) ----------
__global__ __launch_bounds__(256) void k1_parent(
    const float* __restrict__ p0, const float* __restrict__ p1, const float* __restrict__ p2,
    const float* __restrict__ W, const float* __restrict__ b, float* __restrict__ cf) {
  __shared__ float pfs[282];
  __shared__ f32x4 red[320];                    // 256 + 64
  int tid = threadIdx.x;
  pfs[tid] = p0[tid];
  if (tid < 16) pfs[256 + tid] = p1[tid];
  if (tid < 10) pfs[272 + tid] = p2[tid];
  __syncthreads();
  int c = tid & 7, s = tid >> 3;               // 32 k-slices of ~9
  int colg = blockIdx.x * 8 + c;               // f4 column 0..8191
  const f32x4* W4 = (const f32x4*)W;
  int k0 = (s * 282) >> 5, k1e = ((s + 1) * 282) >> 5;
  f32x4 acc = {0.f, 0.f, 0.f, 0.f};
  #pragma unroll 4
  for (int k = k0; k < k1e; ++k)
    acc += pfs[k] * W4[(size_t)k * 8192 + colg];
  red[s * 8 + c] = acc;
  __syncthreads();
  if (tid < 64) {
    int col = tid & 7, part = tid >> 3;        // 8 parts x 4 slices
    f32x4 v = red[(part * 4 + 0) * 8 + col] + red[(part * 4 + 1) * 8 + col]
            + red[(part * 4 + 2) * 8 + col] + red[(part * 4 + 3) * 8 + col];
    red[256 + part * 8 + col] = v;
  }
  __syncthreads();
  if (tid < 8) {
    f32x4 v = red[256 + tid];
    #pragma unroll
    for (int q = 1; q < 8; ++q) v += red[256 + q * 8 + tid];
    v += ((const f32x4*)b)[blockIdx.x * 8 + tid];
    #pragma unroll
    for (int q = 0; q < 4; ++q) v[q] = fmaxf(v[q], 0.f);
    ((f32x4*)cf)[blockIdx.x * 8 + tid] = v;
  }
}

// ---------- ks1: A,B,P0,Q0 matvecs + exists logits + W3T pack. 256 blocks x 1024 thr ----------
__global__ __launch_bounds__(1024) void ks1(
    const float* __restrict__ cf, const float* __restrict__ Wel,
    const float* __restrict__ Wne, const float* __restrict__ bne,
    const float* __restrict__ Wex, const float* __restrict__ bex,
    float* __restrict__ A, float* __restrict__ B, float* __restrict__ P,
    float* __restrict__ Q, float* __restrict__ ex0, float* __restrict__ exout,
    ushort_t* __restrict__ W3T) {
  __shared__ float c[256];
  __shared__ float redA[1024], redB[1024], redP[1024], redQ[1024];
  __shared__ float wsum[4];
  int tid = threadIdx.x;
  int r = blockIdx.x >> 1, half = blockIdx.x & 1;
  if (tid < 256) c[tid] = cf[r * 256 + tid];
  __syncthreads();
  int cc = tid & 127, s = tid >> 7;            // 8 k-slices of 32
  int col = half * 128 + cc;
  int k0 = s * 32;
  const float* WelB = Wel + 256 * 256;
  float aA = 0.f, aB = 0.f, aP = 0.f, aQ = 0.f;
  #pragma unroll 4
  for (int kk = 0; kk < 32; ++kk) {
    int k = k0 + kk;
    float cv = c[k];
    aA += cv * Wel[k * 256 + col];
    aB += cv * WelB[k * 256 + col];
    aP += cv * Wne[k * 256 + col];
    aQ += cv * Wne[(256 + k) * 256 + col];
  }
  redA[tid] = aA; redB[tid] = aB; redP[tid] = aP; redQ[tid] = aQ;
  float v = (half == 0 && tid < 256) ? c[tid] * Wex[tid] : 0.f;
  #pragma unroll
  for (int off = 32; off; off >>= 1) v += __shfl_xor(v, off);
  if (half == 0 && tid < 256 && (tid & 63) == 0) wsum[tid >> 6] = v;
  __syncthreads();
  if (tid < 128) {
    int cl = half * 128 + tid;
    float a = 0.f, bb = 0.f, pv = bne[cl], qv = 0.f;
    #pragma unroll
    for (int q = 0; q < 8; ++q) {
      a  += redA[q * 128 + tid];
      bb += redB[q * 128 + tid];
      pv += redP[q * 128 + tid];
      qv += redQ[q * 128 + tid];
    }
    A[r * 256 + cl] = a;
    B[r * 256 + cl] = bb;
    P[r * 256 + cl] = pv;
    Q[r * 256 + cl] = qv;
  }
  if (half == 0 && tid == 0) {
    float lg = wsum[0] + wsum[1] + wsum[2] + wsum[3] + bex[0];
    exout[r] = lg;
    ex0[r] = lg > 0.f ? 1.f : 0.f;
  }
  if (tid < 512) {                             // pack W3 = Wne[it][512:768] -> bf16 [n][k^s]
    int idx = blockIdx.x * 512 + tid;          // 131072 total
    int it = idx >> 16, n = (idx >> 8) & 255, k = idx & 255;
    W3T[it * 65536 + n * 256 + (k ^ ((n & 7) << 3))] =
        f2bf(Wne[(size_t)(it * 772 + 512 + k) * 256 + n]);
  }
}

// ---------- k3: EL + edge logits, 4 pairs per block. 4096 blocks x 256 ----------
__global__ __launch_bounds__(256) void k3_edge(
    const float* __restrict__ A, const float* __restrict__ B, const float* __restrict__ bel,
    const float* __restrict__ Wee, const float* __restrict__ bee,
    ushort_t* __restrict__ ELbf, float* __restrict__ elog) {
  __shared__ float w4s[4][4][4];               // [jj][wid][t]
  int tid = threadIdx.x, lane = tid & 63, wid = tid >> 6;
  int p0 = blockIdx.x * 4;
  int i = p0 >> 7;                             // same i for all 4 pairs (4 | 128)
  float a = A[i * 256 + tid] + bel[tid];
  float we0 = Wee[tid], we1 = Wee[256 + tid], we2 = Wee[512 + tid], we3 = Wee[768 + tid];
  #pragma unroll
  for (int jj = 0; jj < 4; ++jj) {
    int pr = p0 + jj;
    int j = pr & 127;
    float el = fmaxf(a + B[j * 256 + tid], 0.f);
    ELbf[(size_t)pr * 256 + (tid ^ ((pr & 7) << 3))] = f2bf(el);
    float t0 = el * we0, t1 = el * we1, t2 = el * we2, t3 = el * we3;
    #pragma unroll
    for (int off = 32; off; off >>= 1) {
      t0 += __shfl_xor(t0, off);
      t1 += __shfl_xor(t1, off);
      t2 += __shfl_xor(t2, off);
      t3 += __shfl_xor(t3, off);
    }
    if (lane == 0) { w4s[jj][wid][0] = t0; w4s[jj][wid][1] = t1;
                     w4s[jj][wid][2] = t2; w4s[jj][wid][3] = t3; }
  }
  __syncthreads();
  if (tid < 16) {
    int jj = tid >> 2, t = tid & 3;
    float v = w4s[jj][0][t] + w4s[jj][1][t] + w4s[jj][2][t] + w4s[jj][3][t] + bee[t];
    elog[(p0 + jj) * 4 + t] = v;
  }
}

// ---------- kf_row: per-row fused GEMM(128x256 @ 256x256) + scatter-max + epilogue ----------
// MODE 0: epilogue computes P1,Q1 = cf_row @ WneN (+bne_n)  [kp1 fused]
// MODE 1: epilogue computes h/out_co/sem                     [k6_final fused]
template<int MODE>
__global__ __launch_bounds__(512) void kf_row(
    const ushort_t* __restrict__ ELbf, const ushort_t* __restrict__ W3T_it,
    const float* __restrict__ Wne_it, const float* __restrict__ P,
    const float* __restrict__ Q, const float* __restrict__ ex0,
    const float* __restrict__ elog, float* __restrict__ cfn,
    float* __restrict__ Pn, float* __restrict__ Qn,
    const float* __restrict__ bne_n, const float* __restrict__ WneN,
    const float* __restrict__ cf0, const float* __restrict__ cf1,
    const float* __restrict__ Wc, const float* __restrict__ bc,
    const float* __restrict__ W2, const float* __restrict__ b2,
    const float* __restrict__ Wsem, const float* __restrict__ bsem,
    float* __restrict__ out) {
  __shared__ __align__(16) ushort_t lA[128 * 64];   // 16 KB (also reused as float af[768] in MODE1)
  __shared__ __align__(16) ushort_t lB[256 * 64];   // 32 KB
  __shared__ float sl[512];
  __shared__ float se[128];
  __shared__ float redm[512];
  __shared__ float cfrow[256];
  __shared__ float hrow[256];
  int tid = threadIdx.x;
  int i = blockIdx.x;
  int lane = tid & 63, wid = tid >> 6;
  int wr = wid >> 2, wc = wid & 3;             // 2 x 4 wave grid, 64x64 tiles
  bool alive = ex0[i] != 0.f;                  // block-uniform
  if (alive) {
    sl[tid] = elog[i * 512 + tid];
    if (tid < 128) se[tid] = ex0[tid];
    f32x4 acc[4][4] = {};
    for (int ks = 0; ks < 256; ks += 64) {
      __syncthreads();
      #pragma unroll
      for (int rr = 0; rr < 2; ++rr) {         // lA chunks 0..15
        int c = rr * 8 + wid;
        int row = c * 8 + (lane >> 3);
        int co = (lane & 7) * 8;
        const ushort_t* sa = ELbf + (size_t)(i * 128 + row) * 256 + ks + co;
        __builtin_amdgcn_global_load_lds((const __attribute__((address_space(1))) void*)sa,
                                         (__attribute__((address_space(3))) void*)(lA + c * 512), 16, 0, 0);
      }
      #pragma unroll
      for (int rr = 0; rr < 4; ++rr) {         // lB chunks 0..31
        int c = rr * 8 + wid;
        int row = c * 8 + (lane >> 3);
        int co = (lane & 7) * 8;
        const ushort_t* sb = W3T_it + (size_t)row * 256 + ks + co;
        __builtin_amdgcn_global_load_lds((const __attribute__((address_space(1))) void*)sb,
                                         (__attribute__((address_space(3))) void*)(lB + c * 512), 16, 0, 0);
      }
      __syncthreads();
      #pragma unroll
      for (int kk = 0; kk < 2; ++kk) {
        s16x8 af[4], bfr[4];
        #pragma unroll
        for (int mt = 0; mt < 4; ++mt) {
          int row = wr * 64 + mt * 16 + (lane & 15);
          int kl = (kk * 32 + (lane >> 4) * 8) ^ ((row & 7) << 3);
          af[mt] = *reinterpret_cast<const s16x8*>(&lA[row * 64 + kl]);
        }
        #pragma unroll
        for (int nt = 0; nt < 4; ++nt) {
          int n = wc * 64 + nt * 16 + (lane & 15);
          int kl = (kk * 32 + (lane >> 4) * 8) ^ ((n & 7) << 3);
          bfr[nt] = *reinterpret_cast<const s16x8*>(&lB[n * 64 + kl]);
        }
        #pragma unroll
        for (int mt = 0; mt < 4; ++mt)
          #pragma unroll
          for (int nt = 0; nt < 4; ++nt)
            acc[mt][nt] = __builtin_amdgcn_mfma_f32_16x16x32_bf16(af[mt], bfr[nt], acc[mt][nt], 0, 0, 0);
      }
    }
    __syncthreads();
    const float NEG = -3.0e38f;
    #pragma unroll
    for (int nt = 0; nt < 4; ++nt) {
      int col = wc * 64 + nt * 16 + (lane & 15);
      float w40 = Wne_it[768 * 256 + col];
      float w41 = Wne_it[769 * 256 + col];
      float w42 = Wne_it[770 * 256 + col];
      float w43 = Wne_it[771 * 256 + col];
      float mx = NEG;
      #pragma unroll
      for (int mt = 0; mt < 4; ++mt)
        #pragma unroll
        for (int r = 0; r < 4; ++r) {
          int j = wr * 64 + mt * 16 + (lane >> 4) * 4 + r;
          float base = acc[mt][nt][r] + Q[j * 256 + col];
          float sej = se[j];
          float l0 = sl[j * 4 + 0], l1 = sl[j * 4 + 1];
          float l2 = sl[j * 4 + 2], l3 = sl[j * 4 + 3];
          if (sej > 0.f) {
            if (l0 > 0.f) mx = fmaxf(mx, base + l0 * w40);
            if (l1 > 0.f) mx = fmaxf(mx, base + l1 * w41);
            if (l2 > 0.f) mx = fmaxf(mx, base + l2 * w42);
            if (l3 > 0.f) mx = fmaxf(mx, base + l3 * w43);
          }
        }
      mx = fmaxf(mx, __shfl_xor(mx, 16));
      mx = fmaxf(mx, __shfl_xor(mx, 32));
      if (lane < 16) redm[wr * 256 + col] = mx;
    }
    __syncthreads();
    if (tid < 256) {
      float m = fmaxf(redm[tid], redm[256 + tid]);
      float v = P[i * 256 + tid] + m;              // P constant over (j,t)
      cfrow[tid] = fmaxf(v, 0.f);                  // -inf + P -> 0 (empty mask)
    }
  } else {
    if (tid < 256) cfrow[tid] = 0.f;
  }
  __syncthreads();
  if (tid < 256) cfn[i * 256 + tid] = cfrow[tid];

  int cc = tid & 255, s = tid >> 8;                // 2 k-slices
  if (MODE == 0) {
    // ---- fused kp1: P1,Q1 = cfrow @ WneN[0:512] (+bne_n) ----
    float aP = 0.f, aQ = 0.f;
    #pragma unroll 4
    for (int kk = 0; kk < 128; ++kk) {
      int k = s * 128 + kk;
      float cv = cfrow[k];
      aP += cv * WneN[k * 256 + cc];
      aQ += cv * WneN[(256 + k) * 256 + cc];
    }
    redm[s * 256 + cc] = aP;
    sl[s * 256 + cc] = aQ;                         // sl reused as scratch (elog use done)
    __syncthreads();
    if (tid < 256) {
      Pn[i * 256 + tid] = bne_n[tid] + redm[tid] + redm[256 + tid];
      Qn[i * 256 + tid] = sl[tid] + sl[256 + tid];
    }
  } else {
    // ---- fused k6_final ----
    float* af = (float*)lA;                        // 768 floats (GEMM use of lA done)
    if (tid < 256) {
      af[tid] = cf0[i * 256 + tid];
      af[256 + tid] = cf1[i * 256 + tid];
      af[512 + tid] = cfrow[tid];
    }
    __syncthreads();
    float acc2 = 0.f;
    #pragma unroll 4
    for (int kk = 0; kk < 384; ++kk) {
      int k = s * 384 + kk;
      acc2 += af[k] * Wc[k * 256 + cc];
    }
    redm[s * 256 + cc] = acc2;
    __syncthreads();
    if (tid < 256) hrow[tid] = fmaxf(bc[tid] + redm[tid] + redm[256 + tid], 0.f);
    __syncthreads();
    float acc3 = 0.f;
    #pragma unroll 4
    for (int kk = 0; kk < 128; ++kk) {
      int k = s * 128 + kk;
      acc3 += hrow[k] * W2[k * 256 + cc];
    }
    redm[s * 256 + cc] = acc3;
    float accS = 0.f;
    if (cc < 57) {
      #pragma unroll 4
      for (int kk = 0; kk < 128; ++kk) {
        int k = s * 128 + kk;
        accS += hrow[k] * Wsem[k * 57 + cc];
      }
      sl[s * 64 + cc] = accS;
    }
    __syncthreads();
    if (tid < 256)
      out[i * 256 + tid] = fmaxf(b2[tid] + redm[tid] + redm[256 + tid], 0.f);
    if (tid < 57)
      out[32768 + i * 57 + tid] = bsem[tid] + sl[tid] + sl[64 + tid];
  }
}

extern "C" void kernel_launch(void* const* d_in, const int* in_sizes, int n_in,
                              void* d_out, int out_size, void* d_ws, size_t ws_size,
                              hipStream_t stream) {
  const float* p0  = (const float*)d_in[0];
  const float* p1  = (const float*)d_in[1];
  const float* p2  = (const float*)d_in[2];
  const float* Wp  = (const float*)d_in[3];
  const float* bp  = (const float*)d_in[4];
  const float* Wex = (const float*)d_in[5];
  const float* bex = (const float*)d_in[6];
  const float* Wsm = (const float*)d_in[7];
  const float* bsm = (const float*)d_in[8];
  const float* Wel = (const float*)d_in[9];
  const float* bel = (const float*)d_in[10];
  const float* Wee = (const float*)d_in[11];
  const float* bee = (const float*)d_in[12];
  const float* Wne = (const float*)d_in[13];
  const float* bne = (const float*)d_in[14];
  const float* Wc  = (const float*)d_in[15];
  const float* bc  = (const float*)d_in[16];
  const float* W2  = (const float*)d_in[17];
  const float* b2  = (const float*)d_in[18];
  float* out = (float*)d_out;

  char* ws = (char*)d_ws;
  float*    cf0  = (float*)(ws + 0);
  float*    cf1  = (float*)(ws + 131072);
  float*    cf2  = (float*)(ws + 262144);
  float*    Ab   = (float*)(ws + 393216);
  float*    Bb   = (float*)(ws + 524288);
  float*    Pb   = (float*)(ws + 655360);
  float*    Qb   = (float*)(ws + 786432);
  float*    Pb2  = (float*)(ws + 917504);
  float*    Qb2  = (float*)(ws + 1048576);
  float*    ex0  = (float*)(ws + 1179648);
  ushort_t* W3T  = (ushort_t*)(ws + 1310720);  // 256K
  ushort_t* ELbf = (ushort_t*)(ws + 2097152);  // 8M

  float* out_ex = out + 40064;                 // [128]
  float* out_el = out + 40192;                 // [128,128,4]

  const float* Wne1 = Wne + 772 * 256;

  k1_parent<<<1024, 256, 0, stream>>>(p0, p1, p2, Wp, bp, cf0);
  ks1<<<256, 1024, 0, stream>>>(cf0, Wel, Wne, bne, Wex, bex,
                                Ab, Bb, Pb, Qb, ex0, out_ex, W3T);
  k3_edge<<<4096, 256, 0, stream>>>(Ab, Bb, bel, Wee, bee, ELbf, out_el);
  kf_row<0><<<128, 512, 0, stream>>>(ELbf, W3T, Wne, Pb, Qb, ex0, out_el, cf1,
                                     Pb2, Qb2, bne + 256, Wne1,
                                     nullptr, nullptr, nullptr, nullptr,
                                     nullptr, nullptr, nullptr, nullptr, nullptr);
  kf_row<1><<<128, 512, 0, stream>>>(ELbf, W3T + 65536, Wne1, Pb2, Qb2, ex0, out_el, cf2,
                                     nullptr, nullptr, nullptr, nullptr,
                                     cf0, cf1, Wc, bc, W2, b2, Wsm, bsm, out);
}

// Round 9
// 187.823 us; speedup vs baseline: 1.1800x; 1.1800x over previous
//
#include <hip/hip_runtime.h>
#include <hip/hip_bf16.h>
#include <stdint.h>

// RecursiveDecoder. M=128, H=F=256, T=4, ITERS=2, NSEM=57.
// R7 lesson: per-row fusion (128 blocks) left half the GPU idle and made the
// fused weight-matvec epilogues latency-bound at 0.5 block/CU -> kf_row 67us.
// R8: kf redesigned for latency: 256 blocks x 512 thr, FULL K=256 tile staged
// in ONE global_load_lds burst + ONE barrier (128KB LDS), Q/w4/P/sl/se
// prefetched to registers before the barrier; epilogues un-fused back into
// high-TLP kernels (kp1 256x1024, k6 256x1024 with redundant-h).
//   k1   cf0 = relu(pf @ W_parent + b)            [37 MB, HBM-bound]
//   ks1  A,B = cf0@W_el | P0,Q0 = cf0@Wne0 | exists logits | W3T bf16 pack
//   k3   EL = relu(A[i]+B[j]+bel) -> ELbf (bf16 swizzled) + edge logits (fp32)
//   kf   it0: ELbf@W3 (MFMA) + masked scatter-max -> cf1
//   kp1  P1,Q1 = cf1@Wne1
//   kf   it1 -> cf2
//   k6   h = relu([cf0|cf1|cf2]@Wc+bc); out_co = relu(h@W2+b2); sem = h@Wsem+bsem
// Mask-critical (exists/edge logits) fp32; only EL->R path bf16 MFMA.
// ws: cf0 0 | cf1 128K | cf2 256K | A 384K | B 512K | P 640K | Q 768K |
//     Pb2 896K | Qb2 1M | ex0 1.125M | W3T 1.25M (256K) | ELbf 2M (8M)

typedef unsigned short ushort_t;
using f32x4 = __attribute__((ext_vector_type(4))) float;
using s16x8 = __attribute__((ext_vector_type(8))) short;

__device__ __forceinline__ ushort_t f2bf(float x) {
  __hip_bfloat16 h = __float2bfloat16(x);
  return *reinterpret_cast<ushort_t*>(&h);
}

// ---------- k1: cf0 = relu(pf @ W_parent + b). 1024 blocks x (8 f4-cols, 32 k-slices) ----------
__global__ __launch_bounds__(256) void k1_parent(
    const float* __restrict__ p0, const float* __restrict__ p1, const float* __restrict__ p2,
    const float* __restrict__ W, const float* __restrict__ b, float* __restrict__ cf) {
  __shared__ float pfs[282];
  __shared__ f32x4 red[320];                    // 256 + 64
  int tid = threadIdx.x;
  pfs[tid] = p0[tid];
  if (tid < 16) pfs[256 + tid] = p1[tid];
  if (tid < 10) pfs[272 + tid] = p2[tid];
  __syncthreads();
  int c = tid & 7, s = tid >> 3;               // 32 k-slices of ~9
  int colg = blockIdx.x * 8 + c;               // f4 column 0..8191
  const f32x4* W4 = (const f32x4*)W;
  int k0 = (s * 282) >> 5, k1e = ((s + 1) * 282) >> 5;
  f32x4 acc = {0.f, 0.f, 0.f, 0.f};
  #pragma unroll 4
  for (int k = k0; k < k1e; ++k)
    acc += pfs[k] * W4[(size_t)k * 8192 + colg];
  red[s * 8 + c] = acc;
  __syncthreads();
  if (tid < 64) {
    int col = tid & 7, part = tid >> 3;        // 8 parts x 4 slices
    f32x4 v = red[(part * 4 + 0) * 8 + col] + red[(part * 4 + 1) * 8 + col]
            + red[(part * 4 + 2) * 8 + col] + red[(part * 4 + 3) * 8 + col];
    red[256 + part * 8 + col] = v;
  }
  __syncthreads();
  if (tid < 8) {
    f32x4 v = red[256 + tid];
    #pragma unroll
    for (int q = 1; q < 8; ++q) v += red[256 + q * 8 + tid];
    v += ((const f32x4*)b)[blockIdx.x * 8 + tid];
    #pragma unroll
    for (int q = 0; q < 4; ++q) v[q] = fmaxf(v[q], 0.f);
    ((f32x4*)cf)[blockIdx.x * 8 + tid] = v;
  }
}

// ---------- ks1: A,B,P0,Q0 matvecs + exists logits + W3T pack. 256 blocks x 1024 thr ----------
__global__ __launch_bounds__(1024) void ks1(
    const float* __restrict__ cf, const float* __restrict__ Wel,
    const float* __restrict__ Wne, const float* __restrict__ bne,
    const float* __restrict__ Wex, const float* __restrict__ bex,
    float* __restrict__ A, float* __restrict__ B, float* __restrict__ P,
    float* __restrict__ Q, float* __restrict__ ex0, float* __restrict__ exout,
    ushort_t* __restrict__ W3T) {
  __shared__ float c[256];
  __shared__ float redA[1024], redB[1024], redP[1024], redQ[1024];
  __shared__ float wsum[4];
  int tid = threadIdx.x;
  int r = blockIdx.x >> 1, half = blockIdx.x & 1;
  if (tid < 256) c[tid] = cf[r * 256 + tid];
  __syncthreads();
  int cc = tid & 127, s = tid >> 7;            // 8 k-slices of 32
  int col = half * 128 + cc;
  int k0 = s * 32;
  const float* WelB = Wel + 256 * 256;
  float aA = 0.f, aB = 0.f, aP = 0.f, aQ = 0.f;
  #pragma unroll 4
  for (int kk = 0; kk < 32; ++kk) {
    int k = k0 + kk;
    float cv = c[k];
    aA += cv * Wel[k * 256 + col];
    aB += cv * WelB[k * 256 + col];
    aP += cv * Wne[k * 256 + col];
    aQ += cv * Wne[(256 + k) * 256 + col];
  }
  redA[tid] = aA; redB[tid] = aB; redP[tid] = aP; redQ[tid] = aQ;
  float v = (half == 0 && tid < 256) ? c[tid] * Wex[tid] : 0.f;
  #pragma unroll
  for (int off = 32; off; off >>= 1) v += __shfl_xor(v, off);
  if (half == 0 && tid < 256 && (tid & 63) == 0) wsum[tid >> 6] = v;
  __syncthreads();
  if (tid < 128) {
    int cl = half * 128 + tid;
    float a = 0.f, bb = 0.f, pv = bne[cl], qv = 0.f;
    #pragma unroll
    for (int q = 0; q < 8; ++q) {
      a  += redA[q * 128 + tid];
      bb += redB[q * 128 + tid];
      pv += redP[q * 128 + tid];
      qv += redQ[q * 128 + tid];
    }
    A[r * 256 + cl] = a;
    B[r * 256 + cl] = bb;
    P[r * 256 + cl] = pv;
    Q[r * 256 + cl] = qv;
  }
  if (half == 0 && tid == 0) {
    float lg = wsum[0] + wsum[1] + wsum[2] + wsum[3] + bex[0];
    exout[r] = lg;
    ex0[r] = lg > 0.f ? 1.f : 0.f;
  }
  if (tid < 512) {                             // pack W3 = Wne[it][512:768] -> bf16 [n][k^s]
    int idx = blockIdx.x * 512 + tid;          // 131072 total
    int it = idx >> 16, n = (idx >> 8) & 255, k = idx & 255;
    W3T[it * 65536 + n * 256 + (k ^ ((n & 7) << 3))] =
        f2bf(Wne[(size_t)(it * 772 + 512 + k) * 256 + n]);
  }
}

// ---------- k3: EL + edge logits, 4 pairs per block. 4096 blocks x 256 ----------
__global__ __launch_bounds__(256) void k3_edge(
    const float* __restrict__ A, const float* __restrict__ B, const float* __restrict__ bel,
    const float* __restrict__ Wee, const float* __restrict__ bee,
    ushort_t* __restrict__ ELbf, float* __restrict__ elog) {
  __shared__ float w4s[4][4][4];               // [jj][wid][t]
  int tid = threadIdx.x, lane = tid & 63, wid = tid >> 6;
  int p0 = blockIdx.x * 4;
  int i = p0 >> 7;                             // same i for all 4 pairs (4 | 128)
  float a = A[i * 256 + tid] + bel[tid];
  float we0 = Wee[tid], we1 = Wee[256 + tid], we2 = Wee[512 + tid], we3 = Wee[768 + tid];
  #pragma unroll
  for (int jj = 0; jj < 4; ++jj) {
    int pr = p0 + jj;
    int j = pr & 127;
    float el = fmaxf(a + B[j * 256 + tid], 0.f);
    ELbf[(size_t)pr * 256 + (tid ^ ((pr & 7) << 3))] = f2bf(el);
    float t0 = el * we0, t1 = el * we1, t2 = el * we2, t3 = el * we3;
    #pragma unroll
    for (int off = 32; off; off >>= 1) {
      t0 += __shfl_xor(t0, off);
      t1 += __shfl_xor(t1, off);
      t2 += __shfl_xor(t2, off);
      t3 += __shfl_xor(t3, off);
    }
    if (lane == 0) { w4s[jj][wid][0] = t0; w4s[jj][wid][1] = t1;
                     w4s[jj][wid][2] = t2; w4s[jj][wid][3] = t3; }
  }
  __syncthreads();
  if (tid < 16) {
    int jj = tid >> 2, t = tid & 3;
    float v = w4s[jj][0][t] + w4s[jj][1][t] + w4s[jj][2][t] + w4s[jj][3][t] + bee[t];
    elog[(p0 + jj) * 4 + t] = v;
  }
}

// ---------- kf: GEMM(128x256 @ 256x128, bf16 MFMA) + masked scatter-max ----------
// 256 blocks (i, nh) x 512 thr (8 waves, 2x4 over 128x128 tile, wave tile 64x32).
// Full K=256 staged in one global_load_lds burst + one barrier (128 KB LDS);
// Q/w4/P prefetched to registers, sl/se to LDS, all before the barrier.
__global__ __launch_bounds__(512) void kf(
    const ushort_t* __restrict__ ELbf, const ushort_t* __restrict__ W3T_it,
    const float* __restrict__ Wne_it, const float* __restrict__ P,
    const float* __restrict__ Q, const float* __restrict__ ex0,
    const float* __restrict__ elog, float* __restrict__ cfn) {
  __shared__ __align__(16) ushort_t lA[128 * 256];   // 64 KB
  __shared__ __align__(16) ushort_t lB[128 * 256];   // 64 KB
  __shared__ float sl[512];
  __shared__ float se[128];
  __shared__ float red[256];
  int tid = threadIdx.x;
  int i = blockIdx.x >> 1, nh = blockIdx.x & 1;
  if (ex0[i] == 0.f) {                         // block-uniform
    if (tid < 128) cfn[i * 256 + nh * 128 + tid] = 0.f;
    return;
  }
  int lane = tid & 63, wid = tid >> 6;
  int wr = wid >> 2, wc = wid & 3;             // 2 x 4 wave grid
  // ---- prefetches (overlap with staging) ----
  sl[tid] = elog[i * 512 + tid];
  if (tid < 128) se[tid] = ex0[tid];
  float pv = (tid < 128) ? P[i * 256 + nh * 128 + tid] : 0.f;
  float qv[2][16];
  float w4v[2][4];
  #pragma unroll
  for (int nt = 0; nt < 2; ++nt) {
    int col = nh * 128 + wc * 32 + nt * 16 + (lane & 15);
    #pragma unroll
    for (int t = 0; t < 4; ++t) w4v[nt][t] = Wne_it[(768 + t) * 256 + col];
    #pragma unroll
    for (int mt = 0; mt < 4; ++mt)
      #pragma unroll
      for (int r = 0; r < 4; ++r) {
        int j = wr * 64 + mt * 16 + (lane >> 4) * 4 + r;
        qv[nt][mt * 4 + r] = Q[j * 256 + col];
      }
  }
  // ---- stage full A (ELbf rows of i) and B (W3T half) tiles: 16 loads/thread ----
  #pragma unroll
  for (int rr = 0; rr < 8; ++rr) {
    int c = rr * 8 + wid;                      // wave-uniform 1KB chunk 0..63
    const ushort_t* sa = ELbf + (size_t)(i * 128) * 256 + c * 512 + lane * 8;
    const ushort_t* sb = W3T_it + (size_t)(nh * 128) * 256 + c * 512 + lane * 8;
    __builtin_amdgcn_global_load_lds((const __attribute__((address_space(1))) void*)sa,
                                     (__attribute__((address_space(3))) void*)(lA + c * 512), 16, 0, 0);
    __builtin_amdgcn_global_load_lds((const __attribute__((address_space(1))) void*)sb,
                                     (__attribute__((address_space(3))) void*)(lB + c * 512), 16, 0, 0);
  }
  __syncthreads();
  // ---- 8 K-steps of MFMA, all data resident ----
  f32x4 acc[4][2] = {};
  #pragma unroll
  for (int ks = 0; ks < 8; ++ks) {
    s16x8 af[4], bfr[2];
    #pragma unroll
    for (int mt = 0; mt < 4; ++mt) {
      int row = wr * 64 + mt * 16 + (lane & 15);
      int kl = (ks * 32 + (lane >> 4) * 8) ^ ((row & 7) << 3);
      af[mt] = *reinterpret_cast<const s16x8*>(&lA[row * 256 + kl]);
    }
    #pragma unroll
    for (int nt = 0; nt < 2; ++nt) {
      int n = wc * 32 + nt * 16 + (lane & 15);
      int kl = (ks * 32 + (lane >> 4) * 8) ^ ((n & 7) << 3);
      bfr[nt] = *reinterpret_cast<const s16x8*>(&lB[n * 256 + kl]);
    }
    #pragma unroll
    for (int mt = 0; mt < 4; ++mt)
      #pragma unroll
      for (int nt = 0; nt < 2; ++nt)
        acc[mt][nt] = __builtin_amdgcn_mfma_f32_16x16x32_bf16(af[mt], bfr[nt], acc[mt][nt], 0, 0, 0);
  }
  // ---- masked scatter-max epilogue (registers + LDS only) ----
  const float NEG = -3.0e38f;
  #pragma unroll
  for (int nt = 0; nt < 2; ++nt) {
    float mx = NEG;
    #pragma unroll
    for (int mt = 0; mt < 4; ++mt)
      #pragma unroll
      for (int r = 0; r < 4; ++r) {
        int j = wr * 64 + mt * 16 + (lane >> 4) * 4 + r;
        float base = acc[mt][nt][r] + qv[nt][mt * 4 + r];
        if (se[j] > 0.f) {
          float l0 = sl[j * 4 + 0], l1 = sl[j * 4 + 1];
          float l2 = sl[j * 4 + 2], l3 = sl[j * 4 + 3];
          if (l0 > 0.f) mx = fmaxf(mx, base + l0 * w4v[nt][0]);
          if (l1 > 0.f) mx = fmaxf(mx, base + l1 * w4v[nt][1]);
          if (l2 > 0.f) mx = fmaxf(mx, base + l2 * w4v[nt][2]);
          if (l3 > 0.f) mx = fmaxf(mx, base + l3 * w4v[nt][3]);
        }
      }
    mx = fmaxf(mx, __shfl_xor(mx, 16));
    mx = fmaxf(mx, __shfl_xor(mx, 32));
    if (lane < 16) red[wr * 128 + wc * 32 + nt * 16 + lane] = mx;
  }
  __syncthreads();
  if (tid < 128) {
    float m = fmaxf(red[tid], red[128 + tid]);
    cfn[i * 256 + nh * 128 + tid] = fmaxf(pv + m, 0.f);   // -3e38 + pv -> <0 -> 0 (empty mask)
  }
}

// ---------- kp1: P1,Q1 = cf1@Wne1 (+bne1). 256 blocks x 1024 ----------
__global__ __launch_bounds__(1024) void kp1(
    const float* __restrict__ cf, const float* __restrict__ Wne_it,
    const float* __restrict__ bne_it, float* __restrict__ P, float* __restrict__ Q) {
  __shared__ float c[256];
  __shared__ float redP[1024], redQ[1024];
  int tid = threadIdx.x;
  int r = blockIdx.x >> 1, half = blockIdx.x & 1;
  if (tid < 256) c[tid] = cf[r * 256 + tid];
  __syncthreads();
  int cc = tid & 127, s = tid >> 7;
  int col = half * 128 + cc;
  int k0 = s * 32;
  float aP = 0.f, aQ = 0.f;
  #pragma unroll 4
  for (int kk = 0; kk < 32; ++kk) {
    int k = k0 + kk;
    float cv = c[k];
    aP += cv * Wne_it[k * 256 + col];
    aQ += cv * Wne_it[(256 + k) * 256 + col];
  }
  redP[tid] = aP; redQ[tid] = aQ;
  __syncthreads();
  if (tid < 128) {
    int cl = half * 128 + tid;
    float pv = bne_it[cl], qv = 0.f;
    #pragma unroll
    for (int q = 0; q < 8; ++q) { pv += redP[q * 128 + tid]; qv += redQ[q * 128 + tid]; }
    P[r * 256 + cl] = pv;
    Q[r * 256 + cl] = qv;
  }
}

// ---------- k6: fused final. 256 blocks (m, col-half) x 1024 thr; h computed redundantly ----------
__global__ __launch_bounds__(1024) void k6_final(
    const float* __restrict__ cf0, const float* __restrict__ cf1, const float* __restrict__ cf2,
    const float* __restrict__ Wc, const float* __restrict__ bc,
    const float* __restrict__ Wsem, const float* __restrict__ bsem,
    const float* __restrict__ W2, const float* __restrict__ b2,
    float* __restrict__ out) {
  __shared__ float af[768];
  __shared__ float red[1024];
  __shared__ float hrow[256];
  __shared__ float redS[8 * 57];
  int tid = threadIdx.x;
  int m = blockIdx.x >> 1, half = blockIdx.x & 1;
  if (tid < 768) {
    af[tid] = tid < 256 ? cf0[m * 256 + tid]
            : tid < 512 ? cf1[m * 256 + tid - 256]
                        : cf2[m * 256 + tid - 512];
  }
  __syncthreads();
  {                                            // h: full 256 cols, 4 k-slices of 192
    int cc = tid & 255, s = tid >> 8;
    float acc = 0.f;
    #pragma unroll 4
    for (int kk = 0; kk < 192; ++kk) {
      int k = s * 192 + kk;
      acc += af[k] * Wc[k * 256 + cc];
    }
    red[tid] = acc;
  }
  __syncthreads();
  if (tid < 256) {
    float v = bc[tid] + red[tid] + red[256 + tid] + red[512 + tid] + red[768 + tid];
    hrow[tid] = fmaxf(v, 0.f);
  }
  __syncthreads();
  int cc = tid & 127, s = tid >> 7;            // 8 k-slices of 32
  int col = half * 128 + cc;
  {
    float acc = 0.f;
    #pragma unroll 4
    for (int kk = 0; kk < 32; ++kk) {
      int k = s * 32 + kk;
      acc += hrow[k] * W2[k * 256 + col];
    }
    red[tid] = acc;
    if (half == 0 && cc < 57) {
      float accs = 0.f;
      #pragma unroll 4
      for (int kk = 0; kk < 32; ++kk) {
        int k = s * 32 + kk;
        accs += hrow[k] * Wsem[k * 57 + cc];
      }
      redS[s * 57 + cc] = accs;
    }
  }
  __syncthreads();
  if (tid < 128) {
    float v = b2[half * 128 + tid];
    #pragma unroll
    for (int q = 0; q < 8; ++q) v += red[q * 128 + tid];
    out[m * 256 + half * 128 + tid] = fmaxf(v, 0.f);
  }
  if (half == 0 && tid < 57) {
    float v = bsem[tid];
    #pragma unroll
    for (int q = 0; q < 8; ++q) v += redS[q * 57 + tid];
    out[32768 + m * 57 + tid] = v;
  }
}

extern "C" void kernel_launch(void* const* d_in, const int* in_sizes, int n_in,
                              void* d_out, int out_size, void* d_ws, size_t ws_size,
                              hipStream_t stream) {
  const float* p0  = (const float*)d_in[0];
  const float* p1  = (const float*)d_in[1];
  const float* p2  = (const float*)d_in[2];
  const float* Wp  = (const float*)d_in[3];
  const float* bp  = (const float*)d_in[4];
  const float* Wex = (const float*)d_in[5];
  const float* bex = (const float*)d_in[6];
  const float* Wsm = (const float*)d_in[7];
  const float* bsm = (const float*)d_in[8];
  const float* Wel = (const float*)d_in[9];
  const float* bel = (const float*)d_in[10];
  const float* Wee = (const float*)d_in[11];
  const float* bee = (const float*)d_in[12];
  const float* Wne = (const float*)d_in[13];
  const float* bne = (const float*)d_in[14];
  const float* Wc  = (const float*)d_in[15];
  const float* bc  = (const float*)d_in[16];
  const float* W2  = (const float*)d_in[17];
  const float* b2  = (const float*)d_in[18];
  float* out = (float*)d_out;

  char* ws = (char*)d_ws;
  float*    cf0  = (float*)(ws + 0);
  float*    cf1  = (float*)(ws + 131072);
  float*    cf2  = (float*)(ws + 262144);
  float*    Ab   = (float*)(ws + 393216);
  float*    Bb   = (float*)(ws + 524288);
  float*    Pb   = (float*)(ws + 655360);
  float*    Qb   = (float*)(ws + 786432);
  float*    Pb2  = (float*)(ws + 917504);
  float*    Qb2  = (float*)(ws + 1048576);
  float*    ex0  = (float*)(ws + 1179648);
  ushort_t* W3T  = (ushort_t*)(ws + 1310720);  // 256K
  ushort_t* ELbf = (ushort_t*)(ws + 2097152);  // 8M

  float* out_ex = out + 40064;                 // [128]
  float* out_el = out + 40192;                 // [128,128,4]

  const float* Wne1 = Wne + 772 * 256;

  k1_parent<<<1024, 256, 0, stream>>>(p0, p1, p2, Wp, bp, cf0);
  ks1<<<256, 1024, 0, stream>>>(cf0, Wel, Wne, bne, Wex, bex,
                                Ab, Bb, Pb, Qb, ex0, out_ex, W3T);
  k3_edge<<<4096, 256, 0, stream>>>(Ab, Bb, bel, Wee, bee, ELbf, out_el);
  kf<<<256, 512, 0, stream>>>(ELbf, W3T, Wne, Pb, Qb, ex0, out_el, cf1);
  kp1<<<256, 1024, 0, stream>>>(cf1, Wne1, bne + 256, Pb2, Qb2);
  kf<<<256, 512, 0, stream>>>(ELbf, W3T + 65536, Wne1, Pb2, Qb2, ex0, out_el, cf2);
  k6_final<<<256, 1024, 0, stream>>>(cf0, cf1, cf2, Wc, bc, Wsm, bsm, W2, b2, out);
}

// Round 10
// 179.431 us; speedup vs baseline: 1.2352x; 1.0468x over previous
//
#include <hip/hip_runtime.h>
#include <hip/hip_bf16.h>
#include <stdint.h>

// RecursiveDecoder. M=128, H=F=256, T=4, ITERS=2, NSEM=57.
// R9 -> R10: k3 deleted. kf2 rebuilds the EL tile in-LDS from A,B,bel (rank-1
// decomposition EL[i,j]=relu(A[i]+B[j]+bel)), computes fp32 edge logits locally
// (it0 writes out_el; it1 reads it back -> identical masks), stages only W3T
// via global_load_lds. Kills the 4MB ELbf write + 16MB cold read + 1 dispatch.
//   k1     cf0 = relu(pf @ W_parent + b)            [37 MB, HBM-bound]
//   ks1    A,B = cf0@W_el | P0,Q0 = cf0@Wne0 | exists logits | W3T bf16 pack
//   kf2<1> it0: EL in-LDS + elog(fp32, write) + GEMM(MFMA) + scatter-max -> cf1
//   kp1    P1,Q1 = cf1@Wne1
//   kf2<0> it1: EL in-LDS + elog(read) + GEMM + scatter-max -> cf2
//   k6     h = relu([cf0|cf1|cf2]@Wc+bc); out_co = relu(h@W2+b2); sem = h@Wsem+bsem
// Mask-critical (exists/edge logits) fp32; only EL->R path bf16 MFMA.
// ws: cf0 0 | cf1 128K | cf2 256K | A 384K | B 512K | P 640K | Q 768K |
//     Pb2 896K | Qb2 1M | ex0 1.125M | W3T 1.25M (256K)

typedef unsigned short ushort_t;
using f32x4 = __attribute__((ext_vector_type(4))) float;
using s16x8 = __attribute__((ext_vector_type(8))) short;

__device__ __forceinline__ ushort_t f2bf(float x) {
  __hip_bfloat16 h = __float2bfloat16(x);
  return *reinterpret_cast<ushort_t*>(&h);
}

// ---------- k1: cf0 = relu(pf @ W_parent + b). 1024 blocks x (8 f4-cols, 32 k-slices) ----------
__global__ __launch_bounds__(256) void k1_parent(
    const float* __restrict__ p0, const float* __restrict__ p1, const float* __restrict__ p2,
    const float* __restrict__ W, const float* __restrict__ b, float* __restrict__ cf) {
  __shared__ float pfs[282];
  __shared__ f32x4 red[320];                    // 256 + 64
  int tid = threadIdx.x;
  pfs[tid] = p0[tid];
  if (tid < 16) pfs[256 + tid] = p1[tid];
  if (tid < 10) pfs[272 + tid] = p2[tid];
  __syncthreads();
  int c = tid & 7, s = tid >> 3;               // 32 k-slices of ~9
  int colg = blockIdx.x * 8 + c;               // f4 column 0..8191
  const f32x4* W4 = (const f32x4*)W;
  int k0 = (s * 282) >> 5, k1e = ((s + 1) * 282) >> 5;
  f32x4 acc = {0.f, 0.f, 0.f, 0.f};
  #pragma unroll 4
  for (int k = k0; k < k1e; ++k)
    acc += pfs[k] * W4[(size_t)k * 8192 + colg];
  red[s * 8 + c] = acc;
  __syncthreads();
  if (tid < 64) {
    int col = tid & 7, part = tid >> 3;        // 8 parts x 4 slices
    f32x4 v = red[(part * 4 + 0) * 8 + col] + red[(part * 4 + 1) * 8 + col]
            + red[(part * 4 + 2) * 8 + col] + red[(part * 4 + 3) * 8 + col];
    red[256 + part * 8 + col] = v;
  }
  __syncthreads();
  if (tid < 8) {
    f32x4 v = red[256 + tid];
    #pragma unroll
    for (int q = 1; q < 8; ++q) v += red[256 + q * 8 + tid];
    v += ((const f32x4*)b)[blockIdx.x * 8 + tid];
    #pragma unroll
    for (int q = 0; q < 4; ++q) v[q] = fmaxf(v[q], 0.f);
    ((f32x4*)cf)[blockIdx.x * 8 + tid] = v;
  }
}

// ---------- ks1: A,B,P0,Q0 matvecs + exists logits + W3T pack. 256 blocks x 1024 thr ----------
__global__ __launch_bounds__(1024) void ks1(
    const float* __restrict__ cf, const float* __restrict__ Wel,
    const float* __restrict__ Wne, const float* __restrict__ bne,
    const float* __restrict__ Wex, const float* __restrict__ bex,
    float* __restrict__ A, float* __restrict__ B, float* __restrict__ P,
    float* __restrict__ Q, float* __restrict__ ex0, float* __restrict__ exout,
    ushort_t* __restrict__ W3T) {
  __shared__ float c[256];
  __shared__ float redA[1024], redB[1024], redP[1024], redQ[1024];
  __shared__ float wsum[4];
  int tid = threadIdx.x;
  int r = blockIdx.x >> 1, half = blockIdx.x & 1;
  if (tid < 256) c[tid] = cf[r * 256 + tid];
  __syncthreads();
  int cc = tid & 127, s = tid >> 7;            // 8 k-slices of 32
  int col = half * 128 + cc;
  int k0 = s * 32;
  const float* WelB = Wel + 256 * 256;
  float aA = 0.f, aB = 0.f, aP = 0.f, aQ = 0.f;
  #pragma unroll 4
  for (int kk = 0; kk < 32; ++kk) {
    int k = k0 + kk;
    float cv = c[k];
    aA += cv * Wel[k * 256 + col];
    aB += cv * WelB[k * 256 + col];
    aP += cv * Wne[k * 256 + col];
    aQ += cv * Wne[(256 + k) * 256 + col];
  }
  redA[tid] = aA; redB[tid] = aB; redP[tid] = aP; redQ[tid] = aQ;
  float v = (half == 0 && tid < 256) ? c[tid] * Wex[tid] : 0.f;
  #pragma unroll
  for (int off = 32; off; off >>= 1) v += __shfl_xor(v, off);
  if (half == 0 && tid < 256 && (tid & 63) == 0) wsum[tid >> 6] = v;
  __syncthreads();
  if (tid < 128) {
    int cl = half * 128 + tid;
    float a = 0.f, bb = 0.f, pv = bne[cl], qv = 0.f;
    #pragma unroll
    for (int q = 0; q < 8; ++q) {
      a  += redA[q * 128 + tid];
      bb += redB[q * 128 + tid];
      pv += redP[q * 128 + tid];
      qv += redQ[q * 128 + tid];
    }
    A[r * 256 + cl] = a;
    B[r * 256 + cl] = bb;
    P[r * 256 + cl] = pv;
    Q[r * 256 + cl] = qv;
  }
  if (half == 0 && tid == 0) {
    float lg = wsum[0] + wsum[1] + wsum[2] + wsum[3] + bex[0];
    exout[r] = lg;
    ex0[r] = lg > 0.f ? 1.f : 0.f;
  }
  if (tid < 512) {                             // pack W3 = Wne[it][512:768] -> bf16 [n][k^s]
    int idx = blockIdx.x * 512 + tid;          // 131072 total
    int it = idx >> 16, n = (idx >> 8) & 255, k = idx & 255;
    W3T[it * 65536 + n * 256 + (k ^ ((n & 7) << 3))] =
        f2bf(Wne[(size_t)(it * 772 + 512 + k) * 256 + n]);
  }
}

// ---------- kf2: EL in-LDS + (elog) + GEMM(128x256 @ 256x128 MFMA) + scatter-max ----------
// 256 blocks (i,nh) x 512 thr. lA (EL bf16, XOR-swizzled) built via ds_write from
// A,B,bel; lB (W3T half) staged via global_load_lds. WRITE_EL=1: compute fp32 edge
// logits + write out_el (nh==0). WRITE_EL=0: read sl from out_el.
template<int WRITE_EL>
__global__ __launch_bounds__(512) void kf2(
    const float* __restrict__ A, const float* __restrict__ Bm,
    const float* __restrict__ bel, const float* __restrict__ Wee,
    const float* __restrict__ bee, const ushort_t* __restrict__ W3T_it,
    const float* __restrict__ Wne_it, const float* __restrict__ P,
    const float* __restrict__ Q, const float* __restrict__ ex0,
    float* __restrict__ elog, float* __restrict__ cfn) {
  __shared__ __align__(16) ushort_t lA[128 * 256];   // 64 KB (EL tile)
  __shared__ __align__(16) ushort_t lB[128 * 256];   // 64 KB (W3T half)
  __shared__ float arow[256], belr[256];
  __shared__ float weer[1024];
  __shared__ float sl[512];
  __shared__ float se[128];
  __shared__ float red[256];
  int tid = threadIdx.x;
  int i = blockIdx.x >> 1, nh = blockIdx.x & 1;
  bool alive = ex0[i] != 0.f;                  // block-uniform
  if (!alive && (WRITE_EL == 0 || nh == 1)) {  // dead + no elog duty: exit now
    if (tid < 128) cfn[i * 256 + nh * 128 + tid] = 0.f;
    return;
  }
  int lane = tid & 63, wid = tid >> 6;
  int wr = wid >> 2, wc = wid & 3;             // 2 x 4 wave grid, wave tile 64x32
  if (alive) {                                 // stage W3T half: 8 gload_lds/thread
    #pragma unroll
    for (int rr = 0; rr < 8; ++rr) {
      int ch = rr * 8 + wid;                   // wave-uniform 1KB chunk 0..63
      const ushort_t* sb = W3T_it + (size_t)(nh * 128) * 256 + ch * 512 + lane * 8;
      __builtin_amdgcn_global_load_lds((const __attribute__((address_space(1))) void*)sb,
                                       (__attribute__((address_space(3))) void*)(lB + ch * 512), 16, 0, 0);
    }
  }
  if (tid < 256) { arow[tid] = A[i * 256 + tid]; belr[tid] = bel[tid]; }
  if (tid < 128) se[tid] = ex0[tid];
  if (WRITE_EL) { weer[tid] = Wee[tid]; weer[512 + tid] = Wee[512 + tid]; }
  else sl[tid] = elog[i * 512 + tid];
  float pv = 0.f;
  float qv[2][16];
  float w4v[2][4];
  if (alive) {                                 // epilogue prefetch (overlaps staging)
    pv = (tid < 128) ? P[i * 256 + nh * 128 + tid] : 0.f;
    #pragma unroll
    for (int nt = 0; nt < 2; ++nt) {
      int col = nh * 128 + wc * 32 + nt * 16 + (lane & 15);
      #pragma unroll
      for (int t = 0; t < 4; ++t) w4v[nt][t] = Wne_it[(768 + t) * 256 + col];
      #pragma unroll
      for (int mt = 0; mt < 4; ++mt)
        #pragma unroll
        for (int r = 0; r < 4; ++r)
          qv[nt][mt * 4 + r] = Q[(wr * 64 + mt * 16 + (lane >> 4) * 4 + r) * 256 + col];
    }
  }
  __syncthreads();
  // ---- EL build: thread (j = tid>>2, quad q = tid&3) owns 64 cols of row j ----
  int j = tid >> 2, q = tid & 3;
  int sw = (j & 7) << 3;
  float lg0 = 0.f, lg1 = 0.f, lg2 = 0.f, lg3 = 0.f;
  const float* Bj = Bm + j * 256;
  #pragma unroll
  for (int ch = 0; ch < 8; ++ch) {
    int c0 = q * 64 + ch * 8;
    float el[8];
    #pragma unroll
    for (int e = 0; e < 8; ++e)
      el[e] = fmaxf(arow[c0 + e] + Bj[c0 + e] + belr[c0 + e], 0.f);
    if (WRITE_EL) {
      #pragma unroll
      for (int e = 0; e < 8; ++e) {
        lg0 += el[e] * weer[c0 + e];
        lg1 += el[e] * weer[256 + c0 + e];
        lg2 += el[e] * weer[512 + c0 + e];
        lg3 += el[e] * weer[768 + c0 + e];
      }
    }
    s16x8 sv;
    #pragma unroll
    for (int e = 0; e < 8; ++e) sv[e] = (short)f2bf(el[e]);
    *reinterpret_cast<s16x8*>(&lA[j * 256 + (c0 ^ sw)]) = sv;   // 2-way bank alias only
  }
  if (WRITE_EL) {                              // quad-reduce (lanes j*4..j*4+3 adjacent)
    lg0 += __shfl_xor(lg0, 1); lg0 += __shfl_xor(lg0, 2);
    lg1 += __shfl_xor(lg1, 1); lg1 += __shfl_xor(lg1, 2);
    lg2 += __shfl_xor(lg2, 1); lg2 += __shfl_xor(lg2, 2);
    lg3 += __shfl_xor(lg3, 1); lg3 += __shfl_xor(lg3, 2);
    if (q == 0) {
      float v0 = lg0 + bee[0], v1 = lg1 + bee[1], v2 = lg2 + bee[2], v3 = lg3 + bee[3];
      sl[j * 4 + 0] = v0; sl[j * 4 + 1] = v1; sl[j * 4 + 2] = v2; sl[j * 4 + 3] = v3;
      if (nh == 0) {                           // out_el written for ALL i (mask-independent)
        elog[(i * 128 + j) * 4 + 0] = v0;
        elog[(i * 128 + j) * 4 + 1] = v1;
        elog[(i * 128 + j) * 4 + 2] = v2;
        elog[(i * 128 + j) * 4 + 3] = v3;
      }
    }
  }
  __syncthreads();
  if (!alive) {                                // only WRITE_EL==1 && nh==0 dead blocks
    if (tid < 128) cfn[i * 256 + tid] = 0.f;
    return;
  }
  // ---- 8 K-steps of MFMA, all data resident ----
  f32x4 acc[4][2] = {};
  #pragma unroll
  for (int ks = 0; ks < 8; ++ks) {
    s16x8 af[4], bfr[2];
    #pragma unroll
    for (int mt = 0; mt < 4; ++mt) {
      int row = wr * 64 + mt * 16 + (lane & 15);
      int kl = (ks * 32 + (lane >> 4) * 8) ^ ((row & 7) << 3);
      af[mt] = *reinterpret_cast<const s16x8*>(&lA[row * 256 + kl]);
    }
    #pragma unroll
    for (int nt = 0; nt < 2; ++nt) {
      int n = wc * 32 + nt * 16 + (lane & 15);
      int kl = (ks * 32 + (lane >> 4) * 8) ^ ((n & 7) << 3);
      bfr[nt] = *reinterpret_cast<const s16x8*>(&lB[n * 256 + kl]);
    }
    #pragma unroll
    for (int mt = 0; mt < 4; ++mt)
      #pragma unroll
      for (int nt = 0; nt < 2; ++nt)
        acc[mt][nt] = __builtin_amdgcn_mfma_f32_16x16x32_bf16(af[mt], bfr[nt], acc[mt][nt], 0, 0, 0);
  }
  // ---- masked scatter-max epilogue (registers + LDS only) ----
  const float NEG = -3.0e38f;
  #pragma unroll
  for (int nt = 0; nt < 2; ++nt) {
    float mx = NEG;
    #pragma unroll
    for (int mt = 0; mt < 4; ++mt)
      #pragma unroll
      for (int r = 0; r < 4; ++r) {
        int jj = wr * 64 + mt * 16 + (lane >> 4) * 4 + r;
        float base = acc[mt][nt][r] + qv[nt][mt * 4 + r];
        if (se[jj] > 0.f) {
          float l0 = sl[jj * 4 + 0], l1 = sl[jj * 4 + 1];
          float l2 = sl[jj * 4 + 2], l3 = sl[jj * 4 + 3];
          if (l0 > 0.f) mx = fmaxf(mx, base + l0 * w4v[nt][0]);
          if (l1 > 0.f) mx = fmaxf(mx, base + l1 * w4v[nt][1]);
          if (l2 > 0.f) mx = fmaxf(mx, base + l2 * w4v[nt][2]);
          if (l3 > 0.f) mx = fmaxf(mx, base + l3 * w4v[nt][3]);
        }
      }
    mx = fmaxf(mx, __shfl_xor(mx, 16));
    mx = fmaxf(mx, __shfl_xor(mx, 32));
    if (lane < 16) red[wr * 128 + wc * 32 + nt * 16 + lane] = mx;
  }
  __syncthreads();
  if (tid < 128) {
    float m = fmaxf(red[tid], red[128 + tid]);
    cfn[i * 256 + nh * 128 + tid] = fmaxf(pv + m, 0.f);   // -3e38 + pv -> <0 -> 0 (empty mask)
  }
}

// ---------- kp1: P1,Q1 = cf1@Wne1 (+bne1). 256 blocks x 1024 ----------
__global__ __launch_bounds__(1024) void kp1(
    const float* __restrict__ cf, const float* __restrict__ Wne_it,
    const float* __restrict__ bne_it, float* __restrict__ P, float* __restrict__ Q) {
  __shared__ float c[256];
  __shared__ float redP[1024], redQ[1024];
  int tid = threadIdx.x;
  int r = blockIdx.x >> 1, half = blockIdx.x & 1;
  if (tid < 256) c[tid] = cf[r * 256 + tid];
  __syncthreads();
  int cc = tid & 127, s = tid >> 7;
  int col = half * 128 + cc;
  int k0 = s * 32;
  float aP = 0.f, aQ = 0.f;
  #pragma unroll 4
  for (int kk = 0; kk < 32; ++kk) {
    int k = k0 + kk;
    float cv = c[k];
    aP += cv * Wne_it[k * 256 + col];
    aQ += cv * Wne_it[(256 + k) * 256 + col];
  }
  redP[tid] = aP; redQ[tid] = aQ;
  __syncthreads();
  if (tid < 128) {
    int cl = half * 128 + tid;
    float pv = bne_it[cl], qv = 0.f;
    #pragma unroll
    for (int q = 0; q < 8; ++q) { pv += redP[q * 128 + tid]; qv += redQ[q * 128 + tid]; }
    P[r * 256 + cl] = pv;
    Q[r * 256 + cl] = qv;
  }
}

// ---------- k6: fused final. 256 blocks (m, col-half) x 1024 thr; h computed redundantly ----------
__global__ __launch_bounds__(1024) void k6_final(
    const float* __restrict__ cf0, const float* __restrict__ cf1, const float* __restrict__ cf2,
    const float* __restrict__ Wc, const float* __restrict__ bc,
    const float* __restrict__ Wsem, const float* __restrict__ bsem,
    const float* __restrict__ W2, const float* __restrict__ b2,
    float* __restrict__ out) {
  __shared__ float af[768];
  __shared__ float red[1024];
  __shared__ float hrow[256];
  __shared__ float redS[8 * 57];
  int tid = threadIdx.x;
  int m = blockIdx.x >> 1, half = blockIdx.x & 1;
  if (tid < 768) {
    af[tid] = tid < 256 ? cf0[m * 256 + tid]
            : tid < 512 ? cf1[m * 256 + tid - 256]
                        : cf2[m * 256 + tid - 512];
  }
  __syncthreads();
  {                                            // h: full 256 cols, 4 k-slices of 192
    int cc = tid & 255, s = tid >> 8;
    float acc = 0.f;
    #pragma unroll 4
    for (int kk = 0; kk < 192; ++kk) {
      int k = s * 192 + kk;
      acc += af[k] * Wc[k * 256 + cc];
    }
    red[tid] = acc;
  }
  __syncthreads();
  if (tid < 256) {
    float v = bc[tid] + red[tid] + red[256 + tid] + red[512 + tid] + red[768 + tid];
    hrow[tid] = fmaxf(v, 0.f);
  }
  __syncthreads();
  int cc = tid & 127, s = tid >> 7;            // 8 k-slices of 32
  int col = half * 128 + cc;
  {
    float acc = 0.f;
    #pragma unroll 4
    for (int kk = 0; kk < 32; ++kk) {
      int k = s * 32 + kk;
      acc += hrow[k] * W2[k * 256 + col];
    }
    red[tid] = acc;
    if (half == 0 && cc < 57) {
      float accs = 0.f;
      #pragma unroll 4
      for (int kk = 0; kk < 32; ++kk) {
        int k = s * 32 + kk;
        accs += hrow[k] * Wsem[k * 57 + cc];
      }
      redS[s * 57 + cc] = accs;
    }
  }
  __syncthreads();
  if (tid < 128) {
    float v = b2[half * 128 + tid];
    #pragma unroll
    for (int q = 0; q < 8; ++q) v += red[q * 128 + tid];
    out[m * 256 + half * 128 + tid] = fmaxf(v, 0.f);
  }
  if (half == 0 && tid < 57) {
    float v = bsem[tid];
    #pragma unroll
    for (int q = 0; q < 8; ++q) v += redS[q * 57 + tid];
    out[32768 + m * 57 + tid] = v;
  }
}

extern "C" void kernel_launch(void* const* d_in, const int* in_sizes, int n_in,
                              void* d_out, int out_size, void* d_ws, size_t ws_size,
                              hipStream_t stream) {
  const float* p0  = (const float*)d_in[0];
  const float* p1  = (const float*)d_in[1];
  const float* p2  = (const float*)d_in[2];
  const float* Wp  = (const float*)d_in[3];
  const float* bp  = (const float*)d_in[4];
  const float* Wex = (const float*)d_in[5];
  const float* bex = (const float*)d_in[6];
  const float* Wsm = (const float*)d_in[7];
  const float* bsm = (const float*)d_in[8];
  const float* Wel = (const float*)d_in[9];
  const float* bel = (const float*)d_in[10];
  const float* Wee = (const float*)d_in[11];
  const float* bee = (const float*)d_in[12];
  const float* Wne = (const float*)d_in[13];
  const float* bne = (const float*)d_in[14];
  const float* Wc  = (const float*)d_in[15];
  const float* bc  = (const float*)d_in[16];
  const float* W2  = (const float*)d_in[17];
  const float* b2  = (const float*)d_in[18];
  float* out = (float*)d_out;

  char* ws = (char*)d_ws;
  float*    cf0  = (float*)(ws + 0);
  float*    cf1  = (float*)(ws + 131072);
  float*    cf2  = (float*)(ws + 262144);
  float*    Ab   = (float*)(ws + 393216);
  float*    Bb   = (float*)(ws + 524288);
  float*    Pb   = (float*)(ws + 655360);
  float*    Qb   = (float*)(ws + 786432);
  float*    Pb2  = (float*)(ws + 917504);
  float*    Qb2  = (float*)(ws + 1048576);
  float*    ex0  = (float*)(ws + 1179648);
  ushort_t* W3T  = (ushort_t*)(ws + 1310720);  // 256K

  float* out_ex = out + 40064;                 // [128]
  float* out_el = out + 40192;                 // [128,128,4]

  const float* Wne1 = Wne + 772 * 256;

  k1_parent<<<1024, 256, 0, stream>>>(p0, p1, p2, Wp, bp, cf0);
  ks1<<<256, 1024, 0, stream>>>(cf0, Wel, Wne, bne, Wex, bex,
                                Ab, Bb, Pb, Qb, ex0, out_ex, W3T);
  kf2<1><<<256, 512, 0, stream>>>(Ab, Bb, bel, Wee, bee, W3T, Wne,
                                  Pb, Qb, ex0, out_el, cf1);
  kp1<<<256, 1024, 0, stream>>>(cf1, Wne1, bne + 256, Pb2, Qb2);
  kf2<0><<<256, 512, 0, stream>>>(Ab, Bb, bel, Wee, bee, W3T + 65536, Wne1,
                                  Pb2, Qb2, ex0, out_el, cf2);
  k6_final<<<256, 1024, 0, stream>>>(cf0, cf1, cf2, Wc, bc, Wsm, bsm, W2, b2, out);
}